// Round 16
// baseline (5339.708 us; speedup 1.0000x reference)
//
#include <hip/hip_runtime.h>

// ---------------------------------------------------------------------------
// Seq2SeqAttentionDecoder — round 16
//  R15: keys/enc LDS staging halved FETCH; still 80% stall. Remaining lever:
//  gate weights read 852 MB/step from L2 (32 b-blocks x same rows) ~= 25us/step
//  at L2 BW. Fix: M=32 MFMA gate phases — block computes a 64-row weight
//  slice for ALL 32 b's (weight row read ONCE/step, 32x traffic cut).
//   * Pg0/Pg1: 96 blocks, per-wave 16 rows: C[32x16] = state[32x1024]@W^T
//     (2 m-frags x 32 k MFMA; A via ldu64 from L3; W plain L2 loads)
//   * Pe0/Pe1: 128 blocks, GRU elementwise from fp32 gate scratch
//   * attn (P12 q+scores, P3 softmax+ctx) unchanged from R15 (LDS keys/enc)
//   * 6 global barriers/step (flag arrive + distributed release)
// ---------------------------------------------------------------------------

#define BB 32
#define TT 64
#define SS 128
#define HH 1024
#define EE 512
#define VV 32000
#define H3 3072
#define NEGV (-1000000.0f)
#define NB 1024         // persistent grid blocks (4/CU exact residency)

typedef __attribute__((ext_vector_type(8))) unsigned short u16x8;
typedef __attribute__((ext_vector_type(4))) unsigned short u16x4;
typedef __attribute__((ext_vector_type(8))) short s16x8;
typedef __attribute__((ext_vector_type(4))) float f32x4;
typedef __attribute__((ext_vector_type(2))) unsigned long long u64x2;

__device__ __forceinline__ unsigned short f2bf(float f) {
  unsigned int u = __builtin_bit_cast(unsigned int, f);
  unsigned int r = (u + 0x7FFFu + ((u >> 16) & 1u)) >> 16;   // RNE
  return (unsigned short)r;
}
__device__ __forceinline__ float bfu(unsigned short u) {
  return __builtin_bit_cast(float, (unsigned int)u << 16);
}
__device__ __forceinline__ float sigm(float x) {
  return 1.f / (1.f + __expf(-x));
}
__device__ __forceinline__ float tanhfast(float x) {
  float ax = fabsf(x);
  float e = __expf(2.f * ax);
  float th = 1.f - 2.f / (e + 1.f);
  return copysignf(th, x);
}

// ---- 2-way bf16 dot (for the small q-projection only) ----
#if defined(__has_builtin)
#if __has_builtin(__builtin_amdgcn_fdot2_f32_bf16)
#define HAVE_DOT2BF 1
#endif
#endif
#ifdef HAVE_DOT2BF
typedef __attribute__((ext_vector_type(2))) __bf16 bf16x2;
__device__ __forceinline__ float dot2bf(unsigned w, unsigned x, float c) {
  return __builtin_amdgcn_fdot2_f32_bf16(__builtin_bit_cast(bf16x2, w),
                                         __builtin_bit_cast(bf16x2, x), c,
                                         false);
}
#else
__device__ __forceinline__ float dot2bf(unsigned w, unsigned x, float c) {
  c = fmaf(bfu((unsigned short)(w & 0xffffu)),
           bfu((unsigned short)(x & 0xffffu)), c);
  c = fmaf(bfu((unsigned short)(w >> 16)), bfu((unsigned short)(x >> 16)), c);
  return c;
}
#endif
__device__ __forceinline__ void dot8(float& acc, uint4 w, uint4 x) {
  acc = dot2bf(w.x, x.x, acc); acc = dot2bf(w.y, x.y, acc);
  acc = dot2bf(w.z, x.z, acc); acc = dot2bf(w.w, x.w, acc);
}

// L3-coherent state access (agent-scope relaxed atomics) — no fences
__device__ __forceinline__ float ldu(const float* p) {
  return __hip_atomic_load((float*)p, __ATOMIC_RELAXED, __HIP_MEMORY_SCOPE_AGENT);
}
__device__ __forceinline__ void stu(float* p, float v) {
  __hip_atomic_store(p, v, __ATOMIC_RELAXED, __HIP_MEMORY_SCOPE_AGENT);
}
__device__ __forceinline__ float2 ldu2(const float* p) {
  unsigned long long v = __hip_atomic_load(
      (const unsigned long long*)p, __ATOMIC_RELAXED, __HIP_MEMORY_SCOPE_AGENT);
  return __builtin_bit_cast(float2, v);
}
__device__ __forceinline__ unsigned long long ldu64(const unsigned short* p) {
  return __hip_atomic_load((const unsigned long long*)p, __ATOMIC_RELAXED,
                           __HIP_MEMORY_SCOPE_AGENT);
}
__device__ __forceinline__ unsigned short ldu16(const unsigned short* p) {
  return __hip_atomic_load((unsigned short*)p, __ATOMIC_RELAXED,
                           __HIP_MEMORY_SCOPE_AGENT);
}
__device__ __forceinline__ void stu16(unsigned short* p, unsigned short v) {
  __hip_atomic_store(p, v, __ATOMIC_RELAXED, __HIP_MEMORY_SCOPE_AGENT);
}

// ---------- init: h0A/h1i = bf16(hidden), zero barrier region ----------
// bar (u32): [0 .. 16384) arrival flags (1024 x 16); [16384 .. 17408) 64
// release lines x 16.
__global__ __launch_bounds__(256) void k_init(const float* __restrict__ hid,
                                              unsigned short* __restrict__ h0A,
                                              unsigned short* __restrict__ h1i,
                                              unsigned* __restrict__ bar) {
  int i = blockIdx.x * 256 + threadIdx.x;
  if (i < BB * HH) h0A[i] = f2bf(hid[i]);
  else if (i < 2 * BB * HH) h1i[i - BB * HH] = f2bf(hid[i]);
  else if (i < 2 * BB * HH + 17472) bar[i - 2 * BB * HH] = 0u;
}

// ---------- gather xs[r=t*B+b][e] = bf16(emb[X[b][t]][e]) ----------
__global__ __launch_bounds__(256) void k_gather(const int* __restrict__ X,
                                                const float* __restrict__ emb,
                                                unsigned short* __restrict__ xs) {
  int idx = blockIdx.x * 256 + threadIdx.x;
  int r = idx >> 7, c4 = (idx & 127) << 2;
  int td = r >> 5, b = r & 31;
  int tok = X[b * TT + td];
  float4 v = *(const float4*)(emb + (size_t)tok * EE + c4);
  ushort4 o;
  o.x = f2bf(v.x); o.y = f2bf(v.y); o.z = f2bf(v.z); o.w = f2bf(v.w);
  *(ushort4*)(xs + (size_t)r * EE + c4) = o;
}

// ---------- fp32 -> packed bf16 (grid = rows) ----------
__global__ __launch_bounds__(256) void k_conv(const float* __restrict__ src,
                                              unsigned short* __restrict__ dst,
                                              int cols4, int ld) {
  int r = blockIdx.x;
  for (int c = threadIdx.x; c < cols4; c += 256) {
    float4 v = *(const float4*)(src + (size_t)r * ld + (size_t)c * 4);
    ushort4 o;
    o.x = f2bf(v.x); o.y = f2bf(v.y); o.z = f2bf(v.z); o.w = f2bf(v.w);
    *(ushort4*)(dst + (size_t)r * cols4 * 4 + (size_t)c * 4) = o;
  }
}

// ---------- bf16 MFMA GEMM (m97 structure): C[M,N] = A@W^T (+bias) ----------
__global__ __launch_bounds__(256) void k_gemm_mfma(
    const unsigned short* __restrict__ A, const unsigned short* __restrict__ W,
    const float* __restrict__ bias, float* __restrict__ C,
    int M, int N, int K, int permuteBT, int outBF16) {
  __shared__ unsigned short As[128 * 32];
  __shared__ unsigned short Bs[128 * 32];
  const int m0 = blockIdx.y * 128, n0 = blockIdx.x * 128;
  const int t = threadIdx.x;
  const int lane = t & 63, w = t >> 6;
  const int wr = w >> 1, wc = w & 1;
  const int fr = lane & 15, fq = lane >> 4;
  const int srow = t >> 2;
  const int scol = (t & 3) * 8;
  f32x4 acc[4][4] = {};
  for (int k0 = 0; k0 < K; k0 += 32) {
#pragma unroll
    for (int i = 0; i < 2; ++i) {
      __builtin_amdgcn_global_load_lds(
          (const __attribute__((address_space(1))) void*)(A + (size_t)(m0 + i * 64 + srow) * K + k0 + scol),
          (__attribute__((address_space(3))) void*)((char*)As + i * 4096 + w * 1024),
          16, 0, 0);
      __builtin_amdgcn_global_load_lds(
          (const __attribute__((address_space(1))) void*)(W + (size_t)(n0 + i * 64 + srow) * K + k0 + scol),
          (__attribute__((address_space(3))) void*)((char*)Bs + i * 4096 + w * 1024),
          16, 0, 0);
    }
    __syncthreads();
    s16x8 af[4], bf[4];
#pragma unroll
    for (int mi = 0; mi < 4; ++mi)
      af[mi] = *(const s16x8*)(As + (wr * 64 + mi * 16 + fr) * 32 + fq * 8);
#pragma unroll
    for (int ni = 0; ni < 4; ++ni)
      bf[ni] = *(const s16x8*)(Bs + (wc * 64 + ni * 16 + fr) * 32 + fq * 8);
#pragma unroll
    for (int mi = 0; mi < 4; ++mi)
#pragma unroll
      for (int ni = 0; ni < 4; ++ni)
        acc[mi][ni] = __builtin_amdgcn_mfma_f32_16x16x32_bf16(
            af[mi], bf[ni], acc[mi][ni], 0, 0, 0);
    __syncthreads();
  }
#pragma unroll
  for (int mi = 0; mi < 4; ++mi) {
#pragma unroll
    for (int ni = 0; ni < 4; ++ni) {
      int gc = n0 + wc * 64 + ni * 16 + fr;
      float bv = bias ? bias[gc] : 0.f;
#pragma unroll
      for (int j = 0; j < 4; ++j) {
        int gm = m0 + wr * 64 + mi * 16 + fq * 4 + j;
        size_t ro = permuteBT ? ((size_t)((gm & 31) * TT + (gm >> 5))) * N
                              : (size_t)gm * N;
        float v = acc[mi][ni][j] + bv;
        if (outBF16) ((unsigned short*)C)[ro + gc] = f2bf(v);
        else         C[ro + gc] = v;
      }
    }
  }
}

// ---------- persistent-kernel M=32 MFMA gate slice (one wave, 16 rows) ----
// rows rbase..rbase+16 of a 6144-row space: [0,3072)=Wih (A=Ai, D=Di),
// [3072,6144)=Whh (A=Ah, D=Dh). C[32x16] via 2 m-frags x 32 k-step MFMA.
__device__ __forceinline__ void gemm_slice(
    int rbase, int lane,
    const unsigned short* __restrict__ Wi, const unsigned short* __restrict__ Wh,
    const unsigned short* __restrict__ Ai, const unsigned short* __restrict__ Ah,
    float* __restrict__ Di, float* __restrict__ Dh) {
  const bool ih = rbase < H3;
  const unsigned short* W = ih ? Wi : Wh;
  const unsigned short* A = ih ? Ai : Ah;
  float* D = ih ? Di : Dh;
  const int rw = ih ? rbase : rbase - H3;
  const int fr = lane & 15, fq = lane >> 4;
  const unsigned short* wrow = W + (size_t)(rw + fr) * HH + fq * 8;
  const unsigned short* ar0 = A + (size_t)fr * HH + fq * 8;
  const unsigned short* ar1 = A + (size_t)(16 + fr) * HH + fq * 8;
  f32x4 acc0 = {0.f, 0.f, 0.f, 0.f}, acc1 = {0.f, 0.f, 0.f, 0.f};
  for (int ks = 0; ks < 32; ++ks) {
    s16x8 bfr = *(const s16x8*)(wrow + ks * 32);        // L2-resident weights
    u64x2 a0, a1;
    a0.x = ldu64(ar0 + ks * 32); a0.y = ldu64(ar0 + ks * 32 + 4);
    a1.x = ldu64(ar1 + ks * 32); a1.y = ldu64(ar1 + ks * 32 + 4);
    acc0 = __builtin_amdgcn_mfma_f32_16x16x32_bf16(
        __builtin_bit_cast(s16x8, a0), bfr, acc0, 0, 0, 0);
    acc1 = __builtin_amdgcn_mfma_f32_16x16x32_bf16(
        __builtin_bit_cast(s16x8, a1), bfr, acc1, 0, 0, 0);
  }
  // C row (b) = mi*16 + fq*4 + j ; col (gate n) = rw + fr  (verified mapping)
#pragma unroll
  for (int j = 0; j < 4; ++j) {
    stu(D + (size_t)(fq * 4 + j) * H3 + rw + fr, acc0[j]);
    stu(D + (size_t)(16 + fq * 4 + j) * H3 + rw + fr, acc1[j]);
  }
}

// ---------- the persistent recurrence kernel ----------
__global__ __launch_bounds__(256, 4) void k_persist(
    const unsigned short* __restrict__ keysb,
    const unsigned short* __restrict__ encb,
    const unsigned short* __restrict__ gi0xb,
    const unsigned short* __restrict__ wqb,
    const unsigned short* __restrict__ wi0, const unsigned short* __restrict__ wh0,
    const unsigned short* __restrict__ wi1, const unsigned short* __restrict__ wh1,
    const float* __restrict__ wv, const int* __restrict__ vlen,
    const unsigned short* __restrict__ h1i,
    const float* __restrict__ bhh0, const float* __restrict__ bih1,
    const float* __restrict__ bhh1,
    float* __restrict__ partial,
    float* __restrict__ gi0f, float* __restrict__ gh0f,
    float* __restrict__ gi1f, float* __restrict__ gh1f,
    unsigned short* __restrict__ ctxb,
    unsigned short* __restrict__ h0A, unsigned short* __restrict__ h0B,
    unsigned short* __restrict__ outsb,
    unsigned* __restrict__ bar) {
  __shared__ unsigned shmxu[512];            // bf16-pair staged row
  __shared__ float qs[32];
  __shared__ float aux[640];                 // 128 scores + 512 partials
  __shared__ unsigned short keysl[128 * 32]; // keys[b] 32-col slice (8 KB)
  __shared__ unsigned short encl[128 * 32];  // enc[b]  32-col slice (8 KB)
  const int bid = blockIdx.x, t = threadIdx.x;
  const int b = bid >> 5, sl = bid & 31;
  const int vb = vlen[b];
  unsigned* rel = bar + 16384;               // 64 release lines x 16 u32
  unsigned ep = 0;

  // ---- one-time: stage this block's keys/enc slices into LDS ----
  for (int i = t; i < 1024; i += 256) {
    int s = i >> 3, q = i & 3;
    if (i & 4) {
      *(u16x4*)(encl + s * 32 + q * 8) =
          *(const u16x4*)(encb + (size_t)(b * SS + s) * HH + sl * 32 + q * 8);
      *(u16x4*)(encl + s * 32 + q * 8 + 4) =
          *(const u16x4*)(encb + (size_t)(b * SS + s) * HH + sl * 32 + q * 8 + 4);
    } else {
      *(u16x4*)(keysl + s * 32 + q * 8) =
          *(const u16x4*)(keysb + (size_t)(b * SS + s) * HH + sl * 32 + q * 8);
      *(u16x4*)(keysl + s * 32 + q * 8 + 4) =
          *(const u16x4*)(keysb + (size_t)(b * SS + s) * HH + sl * 32 + q * 8 + 4);
    }
  }
  __syncthreads();

  // global barrier: flag arrive (own line), block0 collects 1024 flags
  // (4/thread), distributed release over 64 lines (16 waiters each).
#define GBAR() do { ++ep; __syncthreads();                                     \
    if (t == 0)                                                                \
      __hip_atomic_store(bar + bid * 16, ep, __ATOMIC_RELAXED,                 \
                         __HIP_MEMORY_SCOPE_AGENT);                            \
    if (bid == 0) {                                                            \
      _Pragma("unroll")                                                        \
      for (int g = 0; g < 4; ++g)                                              \
        while (__hip_atomic_load(bar + (t + 256 * g) * 16, __ATOMIC_RELAXED,   \
                                 __HIP_MEMORY_SCOPE_AGENT) < ep)               \
          __builtin_amdgcn_s_sleep(1);                                         \
      __syncthreads();                                                         \
      if (t < 64)                                                              \
        __hip_atomic_store(rel + t * 16, ep, __ATOMIC_RELAXED,                 \
                           __HIP_MEMORY_SCOPE_AGENT);                          \
    } else if (t == 0) {                                                       \
      while (__hip_atomic_load(rel + (bid >> 4) * 16, __ATOMIC_RELAXED,        \
                               __HIP_MEMORY_SCOPE_AGENT) < ep)                 \
        __builtin_amdgcn_s_sleep(1);                                           \
    }                                                                          \
    __syncthreads(); } while (0)

  for (int td = 0; td < TT; ++td) {
    const unsigned short* h1old =
        td ? outsb + (size_t)(td - 1) * BB * HH : h1i;
    const unsigned short* h0old = (td & 1) ? h0B : h0A;
    unsigned short*       h0new = (td & 1) ? h0A : h0B;

    // ---- P12: q slice (dot2, per-b) + partial scores (LDS keys) ----
    {
      {
        unsigned long long vx = ldu64(h1old + b * HH + t * 4);
        shmxu[t * 2] = (unsigned)vx; shmxu[t * 2 + 1] = (unsigned)(vx >> 32);
      }
      __syncthreads();
      {
        const int nl = t >> 3, q8 = t & 7;
        const unsigned short* wr = wqb + (size_t)(sl * 32 + nl) * HH + q8 * 8;
        float acc = 0;
#pragma unroll 4
        for (int j = 0; j < 16; ++j) {
          const int ku = q8 * 4 + j * 32;
          uint4 xv = *(const uint4*)(shmxu + ku);
          dot8(acc, *(const uint4*)(wr + j * 64), xv);
        }
        acc += __shfl_xor(acc, 1); acc += __shfl_xor(acc, 2);
        acc += __shfl_xor(acc, 4);
        if (q8 == 0) qs[nl] = acc;
      }
      __syncthreads();
      const int s = t >> 1, hf = t & 1;
      if (s < vb) {
        const unsigned short* kr = keysl + s * 32 + hf * 16;
        const float* wvp = wv + sl * 32 + hf * 16;
        const float* qp = qs + hf * 16;
        float a = 0;
#pragma unroll
        for (int j = 0; j < 4; ++j) {
          u16x4 kv = *(const u16x4*)(kr + j * 4);
          float4 wvv = *(const float4*)(wvp + j * 4);
          a = fmaf(tanhfast(qp[j * 4 + 0] + bfu(kv[0])), wvv.x, a);
          a = fmaf(tanhfast(qp[j * 4 + 1] + bfu(kv[1])), wvv.y, a);
          a = fmaf(tanhfast(qp[j * 4 + 2] + bfu(kv[2])), wvv.z, a);
          a = fmaf(tanhfast(qp[j * 4 + 3] + bfu(kv[3])), wvv.w, a);
        }
        a += __shfl_xor(a, 1);
        if (hf == 0) stu(partial + ((size_t)(b * SS + s)) * 32 + sl, a);
      }
    }
    GBAR();

    // ---- P3: sum partials -> softmax -> ctx slice (LDS enc) ----
    {
      if (t < SS) {
        float sc = NEGV;
        if (t < vb) {
          const float* pp = partial + ((size_t)(b * SS + t)) * 32;
          float s2 = 0;
#pragma unroll
          for (int j = 0; j < 16; ++j) {
            float2 v = ldu2(pp + j * 2);
            s2 += v.x + v.y;
          }
          sc = s2;
        }
        aux[t] = sc;
      }
      __syncthreads();
      float mx = aux[0];
      for (int s = 1; s < vb; ++s) mx = fmaxf(mx, aux[s]);
      float p = (t < SS) ? __expf(aux[t] - mx) : 0.f;
      __syncthreads();
      if (t < SS) aux[t] = p;
      __syncthreads();
      float sum = 0;
      for (int s = 0; s < vb; ++s) sum += aux[s];
      const float inv = 1.f / sum;
      const int cp = t & 15, sg = t >> 4;
      float a0 = 0, a1 = 0;
      const int send = min((sg + 1) * 8, vb);
      for (int s = sg * 8; s < send; ++s) {
        unsigned e2 = *(const unsigned*)(encl + s * 32 + cp * 2);
        float pp = aux[s];
        a0 = fmaf(pp, bfu((unsigned short)(e2 & 0xffffu)), a0);
        a1 = fmaf(pp, bfu((unsigned short)(e2 >> 16)), a1);
      }
      aux[SS + sg * 32 + cp * 2]     = a0;
      aux[SS + sg * 32 + cp * 2 + 1] = a1;
      __syncthreads();
      if (t < 32) {
        float v = 0;
#pragma unroll
        for (int g2 = 0; g2 < 16; ++g2) v += aux[SS + g2 * 32 + t];
        stu16(ctxb + b * HH + sl * 32 + t, f2bf(v * inv));
      }
    }
    GBAR();

    // ---- Pg0: layer-0 gate GEMMs (M=32 MFMA), blocks 0..95 ----
    if (bid < 96)
      gemm_slice(bid * 64 + (t >> 6) * 16, t & 63, wi0, wh0,
                 ctxb, h0old, gi0f, gh0f);
    GBAR();

    // ---- Pe0: GRU layer-0 elementwise -> h0new, blocks 0..127 ----
    if (bid < 128) {
      const int idx = (bid << 8) + t;
      const int eb = idx >> 10, n = idx & 1023;
      const size_t g3 = (size_t)eb * H3 + n;
      const unsigned short* gx = gi0xb + ((size_t)td * BB + eb) * H3;
      float gr = ldu(gi0f + g3)        + bfu(__builtin_nontemporal_load(gx + n));
      float gz = ldu(gi0f + g3 + 1024) + bfu(__builtin_nontemporal_load(gx + HH + n));
      float gn = ldu(gi0f + g3 + 2048) + bfu(__builtin_nontemporal_load(gx + 2 * HH + n));
      float hr = ldu(gh0f + g3)        + bhh0[n];
      float hz = ldu(gh0f + g3 + 1024) + bhh0[HH + n];
      float hn = ldu(gh0f + g3 + 2048) + bhh0[2 * HH + n];
      float r = sigm(gr + hr);
      float z = sigm(gz + hz);
      float nn = tanhfast(gn + r * hn);
      float hp = bfu(ldu16(h0old + eb * HH + n));
      stu16(h0new + eb * HH + n, f2bf((1.f - z) * nn + z * hp));
    }
    GBAR();

    // ---- Pg1: layer-1 gate GEMMs (A = h0new / h1old), blocks 0..95 ----
    if (bid < 96)
      gemm_slice(bid * 64 + (t >> 6) * 16, t & 63, wi1, wh1,
                 h0new, h1old, gi1f, gh1f);
    GBAR();

    // ---- Pe1: GRU layer-1 elementwise -> outsb[td], blocks 0..127 ----
    if (bid < 128) {
      const int idx = (bid << 8) + t;
      const int eb = idx >> 10, n = idx & 1023;
      const size_t g3 = (size_t)eb * H3 + n;
      float gr = ldu(gi1f + g3)        + bih1[n];
      float gz = ldu(gi1f + g3 + 1024) + bih1[HH + n];
      float gn = ldu(gi1f + g3 + 2048) + bih1[2 * HH + n];
      float hr = ldu(gh1f + g3)        + bhh1[n];
      float hz = ldu(gh1f + g3 + 1024) + bhh1[HH + n];
      float hn = ldu(gh1f + g3 + 2048) + bhh1[2 * HH + n];
      float r = sigm(gr + hr);
      float z = sigm(gz + hz);
      float nn = tanhfast(gn + r * hn);
      float hp = bfu(ldu16(h1old + eb * HH + n));
      stu16(outsb + (size_t)td * BB * HH + eb * HH + n,
            f2bf((1.f - z) * nn + z * hp));
    }
    GBAR();
  }
#undef GBAR
}

// ---------------------------------------------------------------------------
extern "C" void kernel_launch(void* const* d_in, const int* in_sizes, int n_in,
                              void* d_out, int out_size, void* d_ws,
                              size_t ws_size, hipStream_t stream) {
  const int*   X    = (const int*)  d_in[0];
  const float* enc  = (const float*)d_in[1];
  const float* hid  = (const float*)d_in[2];
  const int*   vlen = (const int*)  d_in[3];
  const float* emb  = (const float*)d_in[4];
  const float* Wq   = (const float*)d_in[5];
  const float* Wk   = (const float*)d_in[6];
  const float* wv   = (const float*)d_in[7];
  const float* Wih0 = (const float*)d_in[8];
  const float* Whh0 = (const float*)d_in[9];
  const float* bih0 = (const float*)d_in[10];
  const float* bhh0 = (const float*)d_in[11];
  const float* Wih1 = (const float*)d_in[12];
  const float* Whh1 = (const float*)d_in[13];
  const float* bih1 = (const float*)d_in[14];
  const float* bhh1 = (const float*)d_in[15];
  const float* Wout = (const float*)d_in[16];
  const float* bout = (const float*)d_in[17];
  float* out = (float*)d_out;

  // ---- workspace (float offsets), ~70.5 MB ----
  // During persist, [14155776..15990784) (dead xsb/wkb/wih0xb) holds the
  // fp32 gate scratch. woutb overlays [0..16,384,000 f) post-loop.
  float* ws = (float*)d_ws;
  unsigned short* wi0b   = (unsigned short*)ws;                 // 4 gate mats
  unsigned short* wh0b   = wi0b + (size_t)3145728;
  unsigned short* wi1b   = wh0b + (size_t)3145728;
  unsigned short* wh1b   = wi1b + (size_t)3145728;
  unsigned short* wqb    = (unsigned short*)(ws + 6291456);
  unsigned short* gi0xb  = (unsigned short*)(ws + 6815744);
  unsigned short* keysb  = (unsigned short*)(ws + 9961472);
  unsigned short* encb   = (unsigned short*)(ws + 12058624);
  unsigned short* xsb    = (unsigned short*)(ws + 14155776);    // prologue only
  unsigned short* wkb    = (unsigned short*)(ws + 14680064);    // prologue only
  unsigned short* wih0xb = (unsigned short*)(ws + 15204352);    // prologue only
  float*          gi0f   = ws + 14155776;                       // 98,304 f each
  float*          gh0f   = gi0f + 98304;
  float*          gi1f   = gh0f + 98304;
  float*          gh1f   = gi1f + 98304;                        // end 14549..
  unsigned short* woutb  = (unsigned short*)ws;                 // overlay
  unsigned short* outsb  = (unsigned short*)(ws + 16384000);
  unsigned short* h0A    = (unsigned short*)(ws + 17432576);
  unsigned short* h0B    = (unsigned short*)(ws + 17448960);
  unsigned short* h1i    = (unsigned short*)(ws + 17465344);
  unsigned short* ctxb   = (unsigned short*)(ws + 17481728);
  float*          partial= ws + 17498112;                       // 131,072 f
  unsigned*       bar    = (unsigned*)(ws + 17629184);          // 17,472 u32

  k_init<<<325, 256, 0, stream>>>(hid, h0A, h1i, bar);
  k_gather<<<1024, 256, 0, stream>>>(X, emb, xsb);
  // bf16 converts for prologue GEMMs
  k_conv<<<4096, 256, 0, stream>>>(enc, encb, 256, HH);
  k_conv<<<1024, 256, 0, stream>>>(Wk, wkb, 256, HH);
  k_conv<<<3072, 256, 0, stream>>>(Wih0 + HH, wih0xb, 128, HH + EE);
  // keysb = bf16(enc @ Wk^T)
  k_gemm_mfma<<<dim3(8, 32), 256, 0, stream>>>(encb, wkb, nullptr,
                                               (float*)keysb, BB * SS, HH, HH,
                                               0, 1);
  // gi0xb = bf16(xs @ W_ih0[:,H:]^T + b_ih0)  (consumes xsb/wih0xb)
  k_gemm_mfma<<<dim3(24, 16), 256, 0, stream>>>(xsb, wih0xb, bih0,
                                                (float*)gi0xb, TT * BB, H3, EE,
                                                0, 1);
  // recurrent weights -> bf16
  k_conv<<<1024, 256, 0, stream>>>(Wq, wqb, 256, HH);
  k_conv<<<3072, 256, 0, stream>>>(Wih0, wi0b, 256, HH + EE);  // ctx cols only
  k_conv<<<3072, 256, 0, stream>>>(Whh0, wh0b, 256, HH);
  k_conv<<<3072, 256, 0, stream>>>(Wih1, wi1b, 256, HH);
  k_conv<<<3072, 256, 0, stream>>>(Whh1, wh1b, 256, HH);

  // the whole 64-step recurrence, one launch
  k_persist<<<NB, 256, 0, stream>>>(keysb, encb, gi0xb, wqb,
                                    wi0b, wh0b, wi1b, wh1b,
                                    wv, vlen, h1i,
                                    bhh0, bih1, bhh1,
                                    partial, gi0f, gh0f, gi1f, gh1f,
                                    ctxb, h0A, h0B, outsb, bar);

  // Wout -> bf16 into the now-dead overlay, then MFMA logits GEMM
  k_conv<<<32000, 256, 0, stream>>>(Wout, woutb, 256, HH);
  k_gemm_mfma<<<dim3(250, 16), 256, 0, stream>>>(outsb, woutb, bout, out,
                                                 TT * BB, VV, HH, 1, 0);
}

// Round 17
// 5098.711 us; speedup vs baseline: 1.0473x; 1.0473x over previous
//
#include <hip/hip_runtime.h>

// ---------------------------------------------------------------------------
// Seq2SeqAttentionDecoder — round 17
//  R16 regressed (96-block MFMA phases starved the machine). Same weight-
//  dedup goal, new shape: gate phases re-tile the SAME 1024 blocks as
//  128 n-slices (8 rows) x 8 b-groups (4 b). GRU applied inline (no scratch,
//  no extra phases; 4 barriers/step). Weight L2 reads drop 32x -> 8x
//  redundancy (806 -> 201 MB/step ~= 6us at L2 BW). State rows for the 4 b's
//  staged in LDS. Barriers become global-scope (gate blocks cross b-groups);
//  R12 showed scope is cost-neutral.
//  attn phases (P12/P3), prologue, logits GEMM identical to R15.
// ---------------------------------------------------------------------------

#define BB 32
#define TT 64
#define SS 128
#define HH 1024
#define EE 512
#define VV 32000
#define H3 3072
#define NEGV (-1000000.0f)
#define NB 1024         // persistent grid blocks (4/CU exact residency)

typedef __attribute__((ext_vector_type(8))) unsigned short u16x8;
typedef __attribute__((ext_vector_type(4))) unsigned short u16x4;
typedef __attribute__((ext_vector_type(8))) short s16x8;
typedef __attribute__((ext_vector_type(4))) float f32x4;

__device__ __forceinline__ unsigned short f2bf(float f) {
  unsigned int u = __builtin_bit_cast(unsigned int, f);
  unsigned int r = (u + 0x7FFFu + ((u >> 16) & 1u)) >> 16;   // RNE
  return (unsigned short)r;
}
__device__ __forceinline__ float bfu(unsigned short u) {
  return __builtin_bit_cast(float, (unsigned int)u << 16);
}
__device__ __forceinline__ float sigm(float x) {
  return 1.f / (1.f + __expf(-x));
}
__device__ __forceinline__ float tanhfast(float x) {
  float ax = fabsf(x);
  float e = __expf(2.f * ax);
  float th = 1.f - 2.f / (e + 1.f);
  return copysignf(th, x);
}

// ---- 2-way bf16 dot product ----
#if defined(__has_builtin)
#if __has_builtin(__builtin_amdgcn_fdot2_f32_bf16)
#define HAVE_DOT2BF 1
#endif
#endif
#ifdef HAVE_DOT2BF
typedef __attribute__((ext_vector_type(2))) __bf16 bf16x2;
__device__ __forceinline__ float dot2bf(unsigned w, unsigned x, float c) {
  return __builtin_amdgcn_fdot2_f32_bf16(__builtin_bit_cast(bf16x2, w),
                                         __builtin_bit_cast(bf16x2, x), c,
                                         false);
}
#else
__device__ __forceinline__ float dot2bf(unsigned w, unsigned x, float c) {
  c = fmaf(bfu((unsigned short)(w & 0xffffu)),
           bfu((unsigned short)(x & 0xffffu)), c);
  c = fmaf(bfu((unsigned short)(w >> 16)), bfu((unsigned short)(x >> 16)), c);
  return c;
}
#endif
__device__ __forceinline__ void dot8(float& acc, uint4 w, uint4 x) {
  acc = dot2bf(w.x, x.x, acc); acc = dot2bf(w.y, x.y, acc);
  acc = dot2bf(w.z, x.z, acc); acc = dot2bf(w.w, x.w, acc);
}

// L3-coherent state access (agent-scope relaxed atomics) — no fences
__device__ __forceinline__ float ldu(const float* p) {
  return __hip_atomic_load((float*)p, __ATOMIC_RELAXED, __HIP_MEMORY_SCOPE_AGENT);
}
__device__ __forceinline__ void stu(float* p, float v) {
  __hip_atomic_store(p, v, __ATOMIC_RELAXED, __HIP_MEMORY_SCOPE_AGENT);
}
__device__ __forceinline__ float2 ldu2(const float* p) {
  unsigned long long v = __hip_atomic_load(
      (const unsigned long long*)p, __ATOMIC_RELAXED, __HIP_MEMORY_SCOPE_AGENT);
  return __builtin_bit_cast(float2, v);
}
__device__ __forceinline__ unsigned long long ldu64(const unsigned short* p) {
  return __hip_atomic_load((const unsigned long long*)p, __ATOMIC_RELAXED,
                           __HIP_MEMORY_SCOPE_AGENT);
}
__device__ __forceinline__ void stu16(unsigned short* p, unsigned short v) {
  __hip_atomic_store(p, v, __ATOMIC_RELAXED, __HIP_MEMORY_SCOPE_AGENT);
}

// ---------- init: h0A/h1i = bf16(hidden), zero barrier region ----------
// bar (u32): [0..16384) arrival flags (1024 x 16); [16384..17408) 64 release
// lines x 16.
__global__ __launch_bounds__(256) void k_init(const float* __restrict__ hid,
                                              unsigned short* __restrict__ h0A,
                                              unsigned short* __restrict__ h1i,
                                              unsigned* __restrict__ bar) {
  int i = blockIdx.x * 256 + threadIdx.x;
  if (i < BB * HH) h0A[i] = f2bf(hid[i]);
  else if (i < 2 * BB * HH) h1i[i - BB * HH] = f2bf(hid[i]);
  else if (i < 2 * BB * HH + 17472) bar[i - 2 * BB * HH] = 0u;
}

// ---------- gather xs[r=t*B+b][e] = bf16(emb[X[b][t]][e]) ----------
__global__ __launch_bounds__(256) void k_gather(const int* __restrict__ X,
                                                const float* __restrict__ emb,
                                                unsigned short* __restrict__ xs) {
  int idx = blockIdx.x * 256 + threadIdx.x;
  int r = idx >> 7, c4 = (idx & 127) << 2;
  int td = r >> 5, b = r & 31;
  int tok = X[b * TT + td];
  float4 v = *(const float4*)(emb + (size_t)tok * EE + c4);
  ushort4 o;
  o.x = f2bf(v.x); o.y = f2bf(v.y); o.z = f2bf(v.z); o.w = f2bf(v.w);
  *(ushort4*)(xs + (size_t)r * EE + c4) = o;
}

// ---------- fp32 -> packed bf16 (grid = rows) ----------
__global__ __launch_bounds__(256) void k_conv(const float* __restrict__ src,
                                              unsigned short* __restrict__ dst,
                                              int cols4, int ld) {
  int r = blockIdx.x;
  for (int c = threadIdx.x; c < cols4; c += 256) {
    float4 v = *(const float4*)(src + (size_t)r * ld + (size_t)c * 4);
    ushort4 o;
    o.x = f2bf(v.x); o.y = f2bf(v.y); o.z = f2bf(v.z); o.w = f2bf(v.w);
    *(ushort4*)(dst + (size_t)r * cols4 * 4 + (size_t)c * 4) = o;
  }
}

// ---------- bf16 MFMA GEMM (m97 structure): C[M,N] = A@W^T (+bias) ----------
__global__ __launch_bounds__(256) void k_gemm_mfma(
    const unsigned short* __restrict__ A, const unsigned short* __restrict__ W,
    const float* __restrict__ bias, float* __restrict__ C,
    int M, int N, int K, int permuteBT, int outBF16) {
  __shared__ unsigned short As[128 * 32];
  __shared__ unsigned short Bs[128 * 32];
  const int m0 = blockIdx.y * 128, n0 = blockIdx.x * 128;
  const int t = threadIdx.x;
  const int lane = t & 63, w = t >> 6;
  const int wr = w >> 1, wc = w & 1;
  const int fr = lane & 15, fq = lane >> 4;
  const int srow = t >> 2;
  const int scol = (t & 3) * 8;
  f32x4 acc[4][4] = {};
  for (int k0 = 0; k0 < K; k0 += 32) {
#pragma unroll
    for (int i = 0; i < 2; ++i) {
      __builtin_amdgcn_global_load_lds(
          (const __attribute__((address_space(1))) void*)(A + (size_t)(m0 + i * 64 + srow) * K + k0 + scol),
          (__attribute__((address_space(3))) void*)((char*)As + i * 4096 + w * 1024),
          16, 0, 0);
      __builtin_amdgcn_global_load_lds(
          (const __attribute__((address_space(1))) void*)(W + (size_t)(n0 + i * 64 + srow) * K + k0 + scol),
          (__attribute__((address_space(3))) void*)((char*)Bs + i * 4096 + w * 1024),
          16, 0, 0);
    }
    __syncthreads();
    s16x8 af[4], bf[4];
#pragma unroll
    for (int mi = 0; mi < 4; ++mi)
      af[mi] = *(const s16x8*)(As + (wr * 64 + mi * 16 + fr) * 32 + fq * 8);
#pragma unroll
    for (int ni = 0; ni < 4; ++ni)
      bf[ni] = *(const s16x8*)(Bs + (wc * 64 + ni * 16 + fr) * 32 + fq * 8);
#pragma unroll
    for (int mi = 0; mi < 4; ++mi)
#pragma unroll
      for (int ni = 0; ni < 4; ++ni)
        acc[mi][ni] = __builtin_amdgcn_mfma_f32_16x16x32_bf16(
            af[mi], bf[ni], acc[mi][ni], 0, 0, 0);
    __syncthreads();
  }
#pragma unroll
  for (int mi = 0; mi < 4; ++mi) {
#pragma unroll
    for (int ni = 0; ni < 4; ++ni) {
      int gc = n0 + wc * 64 + ni * 16 + fr;
      float bv = bias ? bias[gc] : 0.f;
#pragma unroll
      for (int j = 0; j < 4; ++j) {
        int gm = m0 + wr * 64 + mi * 16 + fq * 4 + j;
        size_t ro = permuteBT ? ((size_t)((gm & 31) * TT + (gm >> 5))) * N
                              : (size_t)gm * N;
        float v = acc[mi][ni][j] + bv;
        if (outBF16) ((unsigned short*)C)[ro + gc] = f2bf(v);
        else         C[ro + gc] = v;
      }
    }
  }
}

// ---------- gates + GRU: 8 n-rows x 4 b per block, inline GRU ----------
// Block (nsl = bid&127 -> rows nsl*8..+8; bg = bid>>7 -> b = bg*4..+3).
// Thread (nl = t>>5, bl = (t>>3)&3, k8 = t&7). Weight rows read by 8 blocks
// (was 32). State rows for 4 b's staged in LDS (sx = ih-side, sy = h_prev).
__device__ __forceinline__ void gru_phase(
    int bid, int t, unsigned* sx, unsigned* sy,
    const unsigned short* __restrict__ xg, const unsigned short* __restrict__ hg,
    const unsigned short* __restrict__ wi, const unsigned short* __restrict__ wh,
    const unsigned short* __restrict__ gixbase, const float* __restrict__ bih,
    const float* __restrict__ bhh, unsigned short* __restrict__ hdst) {
  const int n0 = (bid & 127) * 8;
  const int bbase = (bid >> 7) * 4;
  for (int i = t; i < 2048; i += 256) {       // 8 rows x 256 u64 chunks
    int r = i >> 8, c = i & 255;
    int bl = r & 3;
    const unsigned short* src =
        ((r < 4) ? xg : hg) + (size_t)(bbase + bl) * HH + c * 4;
    unsigned long long v = ldu64(src);
    unsigned* dst = ((r < 4) ? sx : sy) + bl * 512 + c * 2;
    dst[0] = (unsigned)v; dst[1] = (unsigned)(v >> 32);
  }
  __syncthreads();
  const int nl = t >> 5, bl = (t >> 3) & 3, k8 = t & 7;
  const int n = n0 + nl;
  const unsigned short* wr = wi + (size_t)n * HH + k8 * 8;
  const unsigned short* hr = wh + (size_t)n * HH + k8 * 8;
  const unsigned* xrow = sx + bl * 512 + k8 * 4;
  const unsigned* yrow = sy + bl * 512 + k8 * 4;
  float air = 0, aiz = 0, ain = 0, ahr = 0, ahz = 0, ahn = 0;
#pragma unroll 4
  for (int j = 0; j < 16; ++j) {              // k = k8*8 + j*64
    uint4 xv = *(const uint4*)(xrow + j * 32);
    uint4 yv = *(const uint4*)(yrow + j * 32);
    const unsigned short* wj = wr + j * 64;
    const unsigned short* hj = hr + j * 64;
    dot8(air, *(const uint4*)(wj),           xv);
    dot8(aiz, *(const uint4*)(wj + 1048576), xv);
    dot8(ain, *(const uint4*)(wj + 2097152), xv);
    dot8(ahr, *(const uint4*)(hj),           yv);
    dot8(ahz, *(const uint4*)(hj + 1048576), yv);
    dot8(ahn, *(const uint4*)(hj + 2097152), yv);
  }
  air += __shfl_xor(air, 1); air += __shfl_xor(air, 2); air += __shfl_xor(air, 4);
  aiz += __shfl_xor(aiz, 1); aiz += __shfl_xor(aiz, 2); aiz += __shfl_xor(aiz, 4);
  ain += __shfl_xor(ain, 1); ain += __shfl_xor(ain, 2); ain += __shfl_xor(ain, 4);
  ahr += __shfl_xor(ahr, 1); ahr += __shfl_xor(ahr, 2); ahr += __shfl_xor(ahr, 4);
  ahz += __shfl_xor(ahz, 1); ahz += __shfl_xor(ahz, 2); ahz += __shfl_xor(ahz, 4);
  ahn += __shfl_xor(ahn, 1); ahn += __shfl_xor(ahn, 2); ahn += __shfl_xor(ahn, 4);
  if (k8 == 0) {
    const int gb = bbase + bl;
    float gr = air, gz = aiz, gn = ain;
    if (gixbase) {
      const unsigned short* gx = gixbase + (size_t)gb * H3;
      gr += bfu(__builtin_nontemporal_load(gx + n));
      gz += bfu(__builtin_nontemporal_load(gx + HH + n));
      gn += bfu(__builtin_nontemporal_load(gx + 2 * HH + n));
    }
    if (bih) { gr += bih[n]; gz += bih[HH + n]; gn += bih[2 * HH + n]; }
    float h_r = ahr + bhh[n], h_z = ahz + bhh[HH + n], h_n = ahn + bhh[2 * HH + n];
    float r = sigm(gr + h_r);
    float z = sigm(gz + h_z);
    float nn = tanhfast(gn + r * h_n);
    unsigned yw = sy[bl * 512 + (n >> 1)];
    float hp = bfu((unsigned short)((n & 1) ? (yw >> 16) : (yw & 0xffffu)));
    stu16(hdst + (size_t)gb * HH + n, f2bf((1.f - z) * nn + z * hp));
  }
}

// ---------- the persistent recurrence kernel ----------
__global__ __launch_bounds__(256, 4) void k_persist(
    const unsigned short* __restrict__ keysb,
    const unsigned short* __restrict__ encb,
    const unsigned short* __restrict__ gi0xb,
    const unsigned short* __restrict__ wqb,
    const unsigned short* __restrict__ wi0, const unsigned short* __restrict__ wh0,
    const unsigned short* __restrict__ wi1, const unsigned short* __restrict__ wh1,
    const float* __restrict__ wv, const int* __restrict__ vlen,
    const unsigned short* __restrict__ h1i,
    const float* __restrict__ bhh0, const float* __restrict__ bih1,
    const float* __restrict__ bhh1,
    float* __restrict__ partial,
    unsigned short* __restrict__ ctxb,
    unsigned short* __restrict__ h0A, unsigned short* __restrict__ h0B,
    unsigned short* __restrict__ outsb,
    unsigned* __restrict__ bar) {
  __shared__ __align__(16) unsigned sx[2048];  // 4 bf16 state rows (8 KB)
  __shared__ __align__(16) unsigned sy[2048];  // 4 bf16 state rows (8 KB)
  __shared__ float qs[32];
  __shared__ float aux[640];                   // 128 scores + 512 partials
  __shared__ unsigned short keysl[128 * 32];   // keys[b] slice (8 KB)
  __shared__ unsigned short encl[128 * 32];    // enc[b]  slice (8 KB)
  const int bid = blockIdx.x, t = threadIdx.x;
  const int b = bid >> 5, sl = bid & 31;       // attn-phase mapping
  const int vb = vlen[b];
  unsigned* rel = bar + 16384;                 // 64 release lines x 16 u32
  unsigned ep = 0;

  // ---- one-time: stage this block's keys/enc slices into LDS ----
  for (int i = t; i < 1024; i += 256) {
    int s = i >> 3, q = i & 3;
    if (i & 4) {
      *(u16x4*)(encl + s * 32 + q * 8) =
          *(const u16x4*)(encb + (size_t)(b * SS + s) * HH + sl * 32 + q * 8);
      *(u16x4*)(encl + s * 32 + q * 8 + 4) =
          *(const u16x4*)(encb + (size_t)(b * SS + s) * HH + sl * 32 + q * 8 + 4);
    } else {
      *(u16x4*)(keysl + s * 32 + q * 8) =
          *(const u16x4*)(keysb + (size_t)(b * SS + s) * HH + sl * 32 + q * 8);
      *(u16x4*)(keysl + s * 32 + q * 8 + 4) =
          *(const u16x4*)(keysb + (size_t)(b * SS + s) * HH + sl * 32 + q * 8 + 4);
    }
  }
  __syncthreads();

  // global flag barrier: arrive = 1 store to own line; block0 collects 1024
  // flags (4/thread); distributed release over 64 lines (16 waiters each).
#define GBAR() do { ++ep; __syncthreads();                                     \
    if (t == 0)                                                                \
      __hip_atomic_store(bar + bid * 16, ep, __ATOMIC_RELAXED,                 \
                         __HIP_MEMORY_SCOPE_AGENT);                            \
    if (bid == 0) {                                                            \
      _Pragma("unroll")                                                        \
      for (int g = 0; g < 4; ++g)                                              \
        while (__hip_atomic_load(bar + (t + 256 * g) * 16, __ATOMIC_RELAXED,   \
                                 __HIP_MEMORY_SCOPE_AGENT) < ep)               \
          __builtin_amdgcn_s_sleep(1);                                         \
      __syncthreads();                                                         \
      if (t < 64)                                                              \
        __hip_atomic_store(rel + t * 16, ep, __ATOMIC_RELAXED,                 \
                           __HIP_MEMORY_SCOPE_AGENT);                          \
    } else if (t == 0) {                                                       \
      while (__hip_atomic_load(rel + (bid >> 4) * 16, __ATOMIC_RELAXED,        \
                               __HIP_MEMORY_SCOPE_AGENT) < ep)                 \
        __builtin_amdgcn_s_sleep(1);                                           \
    }                                                                          \
    __syncthreads(); } while (0)

  for (int td = 0; td < TT; ++td) {
    const unsigned short* h1old =
        td ? outsb + (size_t)(td - 1) * BB * HH : h1i;
    const unsigned short* h0old = (td & 1) ? h0B : h0A;
    unsigned short*       h0new = (td & 1) ? h0A : h0B;

    // ---- P12: q slice (dot2) + partial scores (LDS keys) ----
    {
      {
        unsigned long long vx = ldu64(h1old + b * HH + t * 4);
        sx[t * 2] = (unsigned)vx; sx[t * 2 + 1] = (unsigned)(vx >> 32);
      }
      __syncthreads();
      {
        const int nl = t >> 3, q8 = t & 7;
        const unsigned short* wr = wqb + (size_t)(sl * 32 + nl) * HH + q8 * 8;
        float acc = 0;
#pragma unroll 4
        for (int j = 0; j < 16; ++j) {
          const int ku = q8 * 4 + j * 32;
          uint4 xv = *(const uint4*)(sx + ku);
          dot8(acc, *(const uint4*)(wr + j * 64), xv);
        }
        acc += __shfl_xor(acc, 1); acc += __shfl_xor(acc, 2);
        acc += __shfl_xor(acc, 4);
        if (q8 == 0) qs[nl] = acc;
      }
      __syncthreads();
      const int s = t >> 1, hf = t & 1;
      if (s < vb) {
        const unsigned short* kr = keysl + s * 32 + hf * 16;
        const float* wvp = wv + sl * 32 + hf * 16;
        const float* qp = qs + hf * 16;
        float a = 0;
#pragma unroll
        for (int j = 0; j < 4; ++j) {
          u16x4 kv = *(const u16x4*)(kr + j * 4);
          float4 wvv = *(const float4*)(wvp + j * 4);
          a = fmaf(tanhfast(qp[j * 4 + 0] + bfu(kv[0])), wvv.x, a);
          a = fmaf(tanhfast(qp[j * 4 + 1] + bfu(kv[1])), wvv.y, a);
          a = fmaf(tanhfast(qp[j * 4 + 2] + bfu(kv[2])), wvv.z, a);
          a = fmaf(tanhfast(qp[j * 4 + 3] + bfu(kv[3])), wvv.w, a);
        }
        a += __shfl_xor(a, 1);
        if (hf == 0) stu(partial + ((size_t)(b * SS + s)) * 32 + sl, a);
      }
    }
    GBAR();

    // ---- P3: sum partials -> softmax -> ctx slice (LDS enc) ----
    {
      if (t < SS) {
        float sc = NEGV;
        if (t < vb) {
          const float* pp = partial + ((size_t)(b * SS + t)) * 32;
          float s2 = 0;
#pragma unroll
          for (int j = 0; j < 16; ++j) {
            float2 v = ldu2(pp + j * 2);
            s2 += v.x + v.y;
          }
          sc = s2;
        }
        aux[t] = sc;
      }
      __syncthreads();
      float mx = aux[0];
      for (int s = 1; s < vb; ++s) mx = fmaxf(mx, aux[s]);
      float p = (t < SS) ? __expf(aux[t] - mx) : 0.f;
      __syncthreads();
      if (t < SS) aux[t] = p;
      __syncthreads();
      float sum = 0;
      for (int s = 0; s < vb; ++s) sum += aux[s];
      const float inv = 1.f / sum;
      const int cp = t & 15, sg = t >> 4;
      float a0 = 0, a1 = 0;
      const int send = min((sg + 1) * 8, vb);
      for (int s = sg * 8; s < send; ++s) {
        unsigned e2 = *(const unsigned*)(encl + s * 32 + cp * 2);
        float pp = aux[s];
        a0 = fmaf(pp, bfu((unsigned short)(e2 & 0xffffu)), a0);
        a1 = fmaf(pp, bfu((unsigned short)(e2 >> 16)), a1);
      }
      aux[SS + sg * 32 + cp * 2]     = a0;
      aux[SS + sg * 32 + cp * 2 + 1] = a1;
      __syncthreads();
      if (t < 32) {
        float v = 0;
#pragma unroll
        for (int g2 = 0; g2 < 16; ++g2) v += aux[SS + g2 * 32 + t];
        stu16(ctxb + b * HH + sl * 32 + t, f2bf(v * inv));
      }
    }
    GBAR();

    // ---- P4: layer-0 gates + GRU -> h0new (8n x 4b per block) ----
    gru_phase(bid, t, sx, sy, ctxb, h0old, wi0, wh0,
              gi0xb + (size_t)td * BB * H3, nullptr, bhh0, h0new);
    GBAR();

    // ---- P5: layer-1 gates + GRU -> outsb[td] ----
    gru_phase(bid, t, sx, sy, h0new, h1old, wi1, wh1,
              nullptr, bih1, bhh1, outsb + (size_t)td * BB * HH);
    GBAR();
  }
#undef GBAR
}

// ---------------------------------------------------------------------------
extern "C" void kernel_launch(void* const* d_in, const int* in_sizes, int n_in,
                              void* d_out, int out_size, void* d_ws,
                              size_t ws_size, hipStream_t stream) {
  const int*   X    = (const int*)  d_in[0];
  const float* enc  = (const float*)d_in[1];
  const float* hid  = (const float*)d_in[2];
  const int*   vlen = (const int*)  d_in[3];
  const float* emb  = (const float*)d_in[4];
  const float* Wq   = (const float*)d_in[5];
  const float* Wk   = (const float*)d_in[6];
  const float* wv   = (const float*)d_in[7];
  const float* Wih0 = (const float*)d_in[8];
  const float* Whh0 = (const float*)d_in[9];
  const float* bih0 = (const float*)d_in[10];
  const float* bhh0 = (const float*)d_in[11];
  const float* Wih1 = (const float*)d_in[12];
  const float* Whh1 = (const float*)d_in[13];
  const float* bih1 = (const float*)d_in[14];
  const float* bhh1 = (const float*)d_in[15];
  const float* Wout = (const float*)d_in[16];
  const float* bout = (const float*)d_in[17];
  float* out = (float*)d_out;

  // ---- workspace (float offsets), ~70.6 MB ----
  float* ws = (float*)d_ws;
  unsigned short* wi0b   = (unsigned short*)ws;                 // 4 gate mats
  unsigned short* wh0b   = wi0b + (size_t)3145728;
  unsigned short* wi1b   = wh0b + (size_t)3145728;
  unsigned short* wh1b   = wi1b + (size_t)3145728;
  unsigned short* wqb    = (unsigned short*)(ws + 6291456);
  unsigned short* gi0xb  = (unsigned short*)(ws + 6815744);
  unsigned short* keysb  = (unsigned short*)(ws + 9961472);
  unsigned short* encb   = (unsigned short*)(ws + 12058624);
  unsigned short* xsb    = (unsigned short*)(ws + 14155776);    // prologue only
  unsigned short* wkb    = (unsigned short*)(ws + 14680064);    // prologue only
  unsigned short* wih0xb = (unsigned short*)(ws + 15204352);    // prologue only
  unsigned short* woutb  = (unsigned short*)ws;                 // overlay
  unsigned short* outsb  = (unsigned short*)(ws + 16384000);
  unsigned short* h0A    = (unsigned short*)(ws + 17432576);
  unsigned short* h0B    = (unsigned short*)(ws + 17448960);
  unsigned short* h1i    = (unsigned short*)(ws + 17465344);
  unsigned short* ctxb   = (unsigned short*)(ws + 17481728);
  float*          partial= ws + 17498112;                       // 131,072 f
  unsigned*       bar    = (unsigned*)(ws + 17629184);          // 17,472 u32

  k_init<<<325, 256, 0, stream>>>(hid, h0A, h1i, bar);
  k_gather<<<1024, 256, 0, stream>>>(X, emb, xsb);
  // bf16 converts for prologue GEMMs
  k_conv<<<4096, 256, 0, stream>>>(enc, encb, 256, HH);
  k_conv<<<1024, 256, 0, stream>>>(Wk, wkb, 256, HH);
  k_conv<<<3072, 256, 0, stream>>>(Wih0 + HH, wih0xb, 128, HH + EE);
  // keysb = bf16(enc @ Wk^T)
  k_gemm_mfma<<<dim3(8, 32), 256, 0, stream>>>(encb, wkb, nullptr,
                                               (float*)keysb, BB * SS, HH, HH,
                                               0, 1);
  // gi0xb = bf16(xs @ W_ih0[:,H:]^T + b_ih0)
  k_gemm_mfma<<<dim3(24, 16), 256, 0, stream>>>(xsb, wih0xb, bih0,
                                                (float*)gi0xb, TT * BB, H3, EE,
                                                0, 1);
  // recurrent weights -> bf16
  k_conv<<<1024, 256, 0, stream>>>(Wq, wqb, 256, HH);
  k_conv<<<3072, 256, 0, stream>>>(Wih0, wi0b, 256, HH + EE);  // ctx cols only
  k_conv<<<3072, 256, 0, stream>>>(Whh0, wh0b, 256, HH);
  k_conv<<<3072, 256, 0, stream>>>(Wih1, wi1b, 256, HH);
  k_conv<<<3072, 256, 0, stream>>>(Whh1, wh1b, 256, HH);

  // the whole 64-step recurrence, one launch
  k_persist<<<NB, 256, 0, stream>>>(keysb, encb, gi0xb, wqb,
                                    wi0b, wh0b, wi1b, wh1b,
                                    wv, vlen, h1i,
                                    bhh0, bih1, bhh1,
                                    partial, ctxb, h0A, h0B, outsb, bar);

  // Wout -> bf16 into the now-dead overlay, then MFMA logits GEMM
  k_conv<<<32000, 256, 0, stream>>>(Wout, woutb, 256, HH);
  k_gemm_mfma<<<dim3(250, 16), 256, 0, stream>>>(outsb, woutb, bout, out,
                                                 TT * BB, VV, HH, 1, 0);
}

// Round 18
// 4403.959 us; speedup vs baseline: 1.2125x; 1.1578x over previous
//
#include <hip/hip_runtime.h>

// ---------------------------------------------------------------------------
// Seq2SeqAttentionDecoder — round 18 (= R15 base + coherent-traffic dedup)
//  R17 post-mortem: 4-way LDS conflicts (bl in address), 4x coherent state
//  reads, global barriers -> regression. Reverted to R15.
//  New in R18 (targets the coherent ldu path, the measured scarce resource):
//   * two-stage score reduce: P3a block sums only its 4 s-rows (512B, was
//     16KB/block of partial reads); P3b softmax reads 128 summed scores.
//     Coherent traffic -15.4 MB/step, +1 group barrier (~1us, proven cheap).
//   * h1old LDS row staged once in P12, reused as P5's y-side (skip restage).
//   * h0old staged during P12 (latency hidden under q/scores compute).
//  5 group barriers/step. All else identical to R15.
// ---------------------------------------------------------------------------

#define BB 32
#define TT 64
#define SS 128
#define HH 1024
#define EE 512
#define VV 32000
#define H3 3072
#define NEGV (-1000000.0f)
#define NB 1024         // persistent grid blocks (4/CU exact residency)

typedef __attribute__((ext_vector_type(8))) unsigned short u16x8;
typedef __attribute__((ext_vector_type(4))) unsigned short u16x4;
typedef __attribute__((ext_vector_type(8))) short s16x8;
typedef __attribute__((ext_vector_type(4))) float f32x4;

__device__ __forceinline__ unsigned short f2bf(float f) {
  unsigned int u = __builtin_bit_cast(unsigned int, f);
  unsigned int r = (u + 0x7FFFu + ((u >> 16) & 1u)) >> 16;   // RNE
  return (unsigned short)r;
}
__device__ __forceinline__ float bfu(unsigned short u) {
  return __builtin_bit_cast(float, (unsigned int)u << 16);
}
__device__ __forceinline__ float sigm(float x) {
  return 1.f / (1.f + __expf(-x));
}
__device__ __forceinline__ float tanhfast(float x) {
  float ax = fabsf(x);
  float e = __expf(2.f * ax);
  float th = 1.f - 2.f / (e + 1.f);
  return copysignf(th, x);
}

// ---- 2-way bf16 dot product ----
#if defined(__has_builtin)
#if __has_builtin(__builtin_amdgcn_fdot2_f32_bf16)
#define HAVE_DOT2BF 1
#endif
#endif
#ifdef HAVE_DOT2BF
typedef __attribute__((ext_vector_type(2))) __bf16 bf16x2;
__device__ __forceinline__ float dot2bf(unsigned w, unsigned x, float c) {
  return __builtin_amdgcn_fdot2_f32_bf16(__builtin_bit_cast(bf16x2, w),
                                         __builtin_bit_cast(bf16x2, x), c,
                                         false);
}
#else
__device__ __forceinline__ float dot2bf(unsigned w, unsigned x, float c) {
  c = fmaf(bfu((unsigned short)(w & 0xffffu)),
           bfu((unsigned short)(x & 0xffffu)), c);
  c = fmaf(bfu((unsigned short)(w >> 16)), bfu((unsigned short)(x >> 16)), c);
  return c;
}
#endif
__device__ __forceinline__ void dot8(float& acc, uint4 w, uint4 x) {
  acc = dot2bf(w.x, x.x, acc); acc = dot2bf(w.y, x.y, acc);
  acc = dot2bf(w.z, x.z, acc); acc = dot2bf(w.w, x.w, acc);
}

// L3-coherent state access (agent-scope relaxed atomics) — no fences
__device__ __forceinline__ float ldu(const float* p) {
  return __hip_atomic_load((float*)p, __ATOMIC_RELAXED, __HIP_MEMORY_SCOPE_AGENT);
}
__device__ __forceinline__ void stu(float* p, float v) {
  __hip_atomic_store(p, v, __ATOMIC_RELAXED, __HIP_MEMORY_SCOPE_AGENT);
}
__device__ __forceinline__ unsigned long long ldu64(const unsigned short* p) {
  return __hip_atomic_load((const unsigned long long*)p, __ATOMIC_RELAXED,
                           __HIP_MEMORY_SCOPE_AGENT);
}
__device__ __forceinline__ void stu16(unsigned short* p, unsigned short v) {
  __hip_atomic_store(p, v, __ATOMIC_RELAXED, __HIP_MEMORY_SCOPE_AGENT);
}

// ---------- init: h0A/h1i = bf16(hidden), zero barrier region ----------
// bar (u32): [0..16384) arrival flags (1024 x 16); [16384..16896) 32 group
// release lines x 16.
__global__ __launch_bounds__(256) void k_init(const float* __restrict__ hid,
                                              unsigned short* __restrict__ h0A,
                                              unsigned short* __restrict__ h1i,
                                              unsigned* __restrict__ bar) {
  int i = blockIdx.x * 256 + threadIdx.x;
  if (i < BB * HH) h0A[i] = f2bf(hid[i]);
  else if (i < 2 * BB * HH) h1i[i - BB * HH] = f2bf(hid[i]);
  else if (i < 2 * BB * HH + 16896) bar[i - 2 * BB * HH] = 0u;
}

// ---------- gather xs[r=t*B+b][e] = bf16(emb[X[b][t]][e]) ----------
__global__ __launch_bounds__(256) void k_gather(const int* __restrict__ X,
                                                const float* __restrict__ emb,
                                                unsigned short* __restrict__ xs) {
  int idx = blockIdx.x * 256 + threadIdx.x;
  int r = idx >> 7, c4 = (idx & 127) << 2;
  int td = r >> 5, b = r & 31;
  int tok = X[b * TT + td];
  float4 v = *(const float4*)(emb + (size_t)tok * EE + c4);
  ushort4 o;
  o.x = f2bf(v.x); o.y = f2bf(v.y); o.z = f2bf(v.z); o.w = f2bf(v.w);
  *(ushort4*)(xs + (size_t)r * EE + c4) = o;
}

// ---------- fp32 -> packed bf16 (grid = rows) ----------
__global__ __launch_bounds__(256) void k_conv(const float* __restrict__ src,
                                              unsigned short* __restrict__ dst,
                                              int cols4, int ld) {
  int r = blockIdx.x;
  for (int c = threadIdx.x; c < cols4; c += 256) {
    float4 v = *(const float4*)(src + (size_t)r * ld + (size_t)c * 4);
    ushort4 o;
    o.x = f2bf(v.x); o.y = f2bf(v.y); o.z = f2bf(v.z); o.w = f2bf(v.w);
    *(ushort4*)(dst + (size_t)r * cols4 * 4 + (size_t)c * 4) = o;
  }
}

// ---------- bf16 MFMA GEMM (m97 structure): C[M,N] = A@W^T (+bias) ----------
__global__ __launch_bounds__(256) void k_gemm_mfma(
    const unsigned short* __restrict__ A, const unsigned short* __restrict__ W,
    const float* __restrict__ bias, float* __restrict__ C,
    int M, int N, int K, int permuteBT, int outBF16) {
  __shared__ unsigned short As[128 * 32];
  __shared__ unsigned short Bs[128 * 32];
  const int m0 = blockIdx.y * 128, n0 = blockIdx.x * 128;
  const int t = threadIdx.x;
  const int lane = t & 63, w = t >> 6;
  const int wr = w >> 1, wc = w & 1;
  const int fr = lane & 15, fq = lane >> 4;
  const int srow = t >> 2;
  const int scol = (t & 3) * 8;
  f32x4 acc[4][4] = {};
  for (int k0 = 0; k0 < K; k0 += 32) {
#pragma unroll
    for (int i = 0; i < 2; ++i) {
      __builtin_amdgcn_global_load_lds(
          (const __attribute__((address_space(1))) void*)(A + (size_t)(m0 + i * 64 + srow) * K + k0 + scol),
          (__attribute__((address_space(3))) void*)((char*)As + i * 4096 + w * 1024),
          16, 0, 0);
      __builtin_amdgcn_global_load_lds(
          (const __attribute__((address_space(1))) void*)(W + (size_t)(n0 + i * 64 + srow) * K + k0 + scol),
          (__attribute__((address_space(3))) void*)((char*)Bs + i * 4096 + w * 1024),
          16, 0, 0);
    }
    __syncthreads();
    s16x8 af[4], bf[4];
#pragma unroll
    for (int mi = 0; mi < 4; ++mi)
      af[mi] = *(const s16x8*)(As + (wr * 64 + mi * 16 + fr) * 32 + fq * 8);
#pragma unroll
    for (int ni = 0; ni < 4; ++ni)
      bf[ni] = *(const s16x8*)(Bs + (wc * 64 + ni * 16 + fr) * 32 + fq * 8);
#pragma unroll
    for (int mi = 0; mi < 4; ++mi)
#pragma unroll
      for (int ni = 0; ni < 4; ++ni)
        acc[mi][ni] = __builtin_amdgcn_mfma_f32_16x16x32_bf16(
            af[mi], bf[ni], acc[mi][ni], 0, 0, 0);
    __syncthreads();
  }
#pragma unroll
  for (int mi = 0; mi < 4; ++mi) {
#pragma unroll
    for (int ni = 0; ni < 4; ++ni) {
      int gc = n0 + wc * 64 + ni * 16 + fr;
      float bv = bias ? bias[gc] : 0.f;
#pragma unroll
      for (int j = 0; j < 4; ++j) {
        int gm = m0 + wr * 64 + mi * 16 + fq * 4 + j;
        size_t ro = permuteBT ? ((size_t)((gm & 31) * TT + (gm >> 5))) * N
                              : (size_t)gm * N;
        float v = acc[mi][ni][j] + bv;
        if (outBF16) ((unsigned short*)C)[ro + gc] = f2bf(v);
        else         C[ro + gc] = v;
      }
    }
  }
}

// ---------- gates + GRU via dot2; 32-n slice, 8-thread k-split ----------
// Stages x into sxu; y is PRE-STAGED (syu). hprev read from syu.
__device__ __forceinline__ void gru_phase(
    int sl, int t, unsigned* sxu, const unsigned* syu,
    const unsigned short* __restrict__ xg,
    const unsigned short* __restrict__ wi, const unsigned short* __restrict__ wh,
    const unsigned short* __restrict__ gixrow, const float* __restrict__ bih,
    const float* __restrict__ bhh, unsigned short* __restrict__ hdst) {
  {
    unsigned long long vx = ldu64(xg + t * 4);
    sxu[t * 2] = (unsigned)vx; sxu[t * 2 + 1] = (unsigned)(vx >> 32);
  }
  __syncthreads();
  const int nl = t >> 3, q8 = t & 7;      // 32 n x 8 k-groups
  const int n = sl * 32 + nl;
  const unsigned short* wr = wi + (size_t)n * HH + q8 * 8;
  const unsigned short* hr = wh + (size_t)n * HH + q8 * 8;
  float air = 0, aiz = 0, ain = 0, ahr = 0, ahz = 0, ahn = 0;
#pragma unroll 2
  for (int j = 0; j < 16; ++j) {
    const int ku = q8 * 4 + j * 32;       // u32 index (8 bf16 = 4 u32)
    uint4 xv = *(const uint4*)(sxu + ku);
    uint4 yv = *(const uint4*)(syu + ku);
    const unsigned short* wj = wr + j * 64;
    const unsigned short* hj = hr + j * 64;
    dot8(air, *(const uint4*)(wj),           xv);
    dot8(aiz, *(const uint4*)(wj + 1048576), xv);
    dot8(ain, *(const uint4*)(wj + 2097152), xv);
    dot8(ahr, *(const uint4*)(hj),           yv);
    dot8(ahz, *(const uint4*)(hj + 1048576), yv);
    dot8(ahn, *(const uint4*)(hj + 2097152), yv);
  }
  air += __shfl_xor(air, 1); air += __shfl_xor(air, 2); air += __shfl_xor(air, 4);
  aiz += __shfl_xor(aiz, 1); aiz += __shfl_xor(aiz, 2); aiz += __shfl_xor(aiz, 4);
  ain += __shfl_xor(ain, 1); ain += __shfl_xor(ain, 2); ain += __shfl_xor(ain, 4);
  ahr += __shfl_xor(ahr, 1); ahr += __shfl_xor(ahr, 2); ahr += __shfl_xor(ahr, 4);
  ahz += __shfl_xor(ahz, 1); ahz += __shfl_xor(ahz, 2); ahz += __shfl_xor(ahz, 4);
  ahn += __shfl_xor(ahn, 1); ahn += __shfl_xor(ahn, 2); ahn += __shfl_xor(ahn, 4);
  if (q8 == 0) {
    float gr = air, gz = aiz, gn = ain;
    if (gixrow) {
      gr += bfu(__builtin_nontemporal_load(gixrow + n));
      gz += bfu(__builtin_nontemporal_load(gixrow + HH + n));
      gn += bfu(__builtin_nontemporal_load(gixrow + 2 * HH + n));
    }
    if (bih) { gr += bih[n]; gz += bih[HH + n]; gn += bih[2 * HH + n]; }
    float h_r = ahr + bhh[n], h_z = ahz + bhh[HH + n], h_n = ahn + bhh[2 * HH + n];
    float r = sigm(gr + h_r);
    float z = sigm(gz + h_z);
    float nn = tanhfast(gn + r * h_n);
    unsigned yw = syu[n >> 1];
    float hp = bfu((unsigned short)((n & 1) ? (yw >> 16) : (yw & 0xffffu)));
    stu16(hdst + n, f2bf((1.f - z) * nn + z * hp));
  }
}

// ---------- the persistent recurrence kernel (per-b 32-block groups) ----------
__global__ __launch_bounds__(256, 4) void k_persist(
    const unsigned short* __restrict__ keysb,
    const unsigned short* __restrict__ encb,
    const unsigned short* __restrict__ gi0xb,
    const unsigned short* __restrict__ wqb,
    const unsigned short* __restrict__ wi0, const unsigned short* __restrict__ wh0,
    const unsigned short* __restrict__ wi1, const unsigned short* __restrict__ wh1,
    const float* __restrict__ wv, const int* __restrict__ vlen,
    const unsigned short* __restrict__ h1i,
    const float* __restrict__ bhh0, const float* __restrict__ bih1,
    const float* __restrict__ bhh1,
    float* __restrict__ partial, float* __restrict__ scores,
    unsigned short* __restrict__ ctxb,
    unsigned short* __restrict__ h0A, unsigned short* __restrict__ h0B,
    unsigned short* __restrict__ outsb,
    unsigned* __restrict__ bar) {
  __shared__ unsigned sh1u[512];             // h1old bf16-pairs (P12 q, P5 y)
  __shared__ unsigned sh0u[512];             // h0old (P4 y), staged in P12
  __shared__ unsigned sxu[512];              // x-side (ctx / h0new)
  __shared__ float qs[32];
  __shared__ float aux[640];                 // 128 scores + 512 ctx partials
  __shared__ unsigned short keysl[128 * 32]; // keys[b] 32-col slice (8 KB)
  __shared__ unsigned short encl[128 * 32];  // enc[b]  32-col slice (8 KB)
  const int bid = blockIdx.x, t = threadIdx.x;
  const int b = bid >> 5, sl = bid & 31;
  const int vb = vlen[b];
  unsigned* rel = bar + 16384;
  unsigned ep = 0;

  // ---- one-time: stage this block's keys/enc slices into LDS ----
  for (int i = t; i < 1024; i += 256) {
    int s = i >> 3, q = i & 3;
    if (i & 4) {
      *(u16x4*)(encl + s * 32 + q * 8) =
          *(const u16x4*)(encb + (size_t)(b * SS + s) * HH + sl * 32 + q * 8);
      *(u16x4*)(encl + s * 32 + q * 8 + 4) =
          *(const u16x4*)(encb + (size_t)(b * SS + s) * HH + sl * 32 + q * 8 + 4);
    } else {
      *(u16x4*)(keysl + s * 32 + q * 8) =
          *(const u16x4*)(keysb + (size_t)(b * SS + s) * HH + sl * 32 + q * 8);
      *(u16x4*)(keysl + s * 32 + q * 8 + 4) =
          *(const u16x4*)(keysb + (size_t)(b * SS + s) * HH + sl * 32 + q * 8 + 4);
    }
  }
  __syncthreads();

  // per-b GROUP barrier (32 blocks), R15-proven
#define GBAR() do { ++ep; __syncthreads();                                     \
    if (t == 0)                                                                \
      __hip_atomic_store(bar + bid * 16, ep, __ATOMIC_RELAXED,                 \
                         __HIP_MEMORY_SCOPE_AGENT);                            \
    if (sl == 0) {                                                             \
      if (t < 32)                                                              \
        while (__hip_atomic_load(bar + (b * 32 + t) * 16, __ATOMIC_RELAXED,    \
                                 __HIP_MEMORY_SCOPE_AGENT) < ep)               \
          __builtin_amdgcn_s_sleep(1);                                         \
      __syncthreads();                                                         \
      if (t == 0)                                                              \
        __hip_atomic_store(rel + b * 16, ep, __ATOMIC_RELAXED,                 \
                           __HIP_MEMORY_SCOPE_AGENT);                          \
    } else if (t == 0) {                                                       \
      while (__hip_atomic_load(rel + b * 16, __ATOMIC_RELAXED,                 \
                               __HIP_MEMORY_SCOPE_AGENT) < ep)                 \
        __builtin_amdgcn_s_sleep(1);                                           \
    }                                                                          \
    __syncthreads(); } while (0)

  for (int td = 0; td < TT; ++td) {
    const unsigned short* h1old =
        td ? outsb + (size_t)(td - 1) * BB * HH : h1i;
    const unsigned short* h0old = (td & 1) ? h0B : h0A;
    unsigned short*       h0new = (td & 1) ? h0A : h0B;

    // ---- P12: stage h1(+h0), q slice (dot2), partial scores (LDS keys) ----
    {
      {
        unsigned long long v1 = ldu64(h1old + b * HH + t * 4);
        unsigned long long v0 = ldu64(h0old + b * HH + t * 4);
        sh1u[t * 2] = (unsigned)v1; sh1u[t * 2 + 1] = (unsigned)(v1 >> 32);
        sh0u[t * 2] = (unsigned)v0; sh0u[t * 2 + 1] = (unsigned)(v0 >> 32);
      }
      __syncthreads();
      {
        const int nl = t >> 3, q8 = t & 7;
        const unsigned short* wr = wqb + (size_t)(sl * 32 + nl) * HH + q8 * 8;
        float acc = 0;
#pragma unroll 4
        for (int j = 0; j < 16; ++j) {
          const int ku = q8 * 4 + j * 32;
          uint4 xv = *(const uint4*)(sh1u + ku);
          dot8(acc, *(const uint4*)(wr + j * 64), xv);
        }
        acc += __shfl_xor(acc, 1); acc += __shfl_xor(acc, 2);
        acc += __shfl_xor(acc, 4);
        if (q8 == 0) qs[nl] = acc;
      }
      __syncthreads();
      const int s = t >> 1, hf = t & 1;
      if (s < vb) {
        const unsigned short* kr = keysl + s * 32 + hf * 16;
        const float* wvp = wv + sl * 32 + hf * 16;
        const float* qp = qs + hf * 16;
        float a = 0;
#pragma unroll
        for (int j = 0; j < 4; ++j) {
          u16x4 kv = *(const u16x4*)(kr + j * 4);
          float4 wvv = *(const float4*)(wvp + j * 4);
          a = fmaf(tanhfast(qp[j * 4 + 0] + bfu(kv[0])), wvv.x, a);
          a = fmaf(tanhfast(qp[j * 4 + 1] + bfu(kv[1])), wvv.y, a);
          a = fmaf(tanhfast(qp[j * 4 + 2] + bfu(kv[2])), wvv.z, a);
          a = fmaf(tanhfast(qp[j * 4 + 3] + bfu(kv[3])), wvv.w, a);
        }
        a += __shfl_xor(a, 1);
        if (hf == 0) stu(partial + ((size_t)(b * SS + s)) * 32 + sl, a);
      }
    }
    GBAR();

    // ---- P3a: block sums its 4 s-rows (32 partials each, 512B coherent) ----
    if (t < 128) {
      const int s = sl * 4 + (t >> 5), g = t & 31;
      float a = 0;
      if (s < vb) {
        a = ldu(partial + ((size_t)(b * SS + s)) * 32 + g);
        a += __shfl_xor(a, 1); a += __shfl_xor(a, 2); a += __shfl_xor(a, 4);
        a += __shfl_xor(a, 8); a += __shfl_xor(a, 16);
      }
      if (g == 0) stu(scores + b * SS + s, (s < vb) ? a : NEGV);
    }
    GBAR();

    // ---- P3b: softmax (512B score reads) -> ctx slice (LDS enc) ----
    {
      if (t < SS) aux[t] = ldu(scores + b * SS + t);
      __syncthreads();
      float mx = aux[0];
      for (int s = 1; s < vb; ++s) mx = fmaxf(mx, aux[s]);
      float p = (t < SS) ? __expf(aux[t] - mx) : 0.f;
      __syncthreads();
      if (t < SS) aux[t] = p;
      __syncthreads();
      float sum = 0;
      for (int s = 0; s < vb; ++s) sum += aux[s];
      const float inv = 1.f / sum;
      const int cp = t & 15, sg = t >> 4;
      float a0 = 0, a1 = 0;
      const int send = min((sg + 1) * 8, vb);
      for (int s = sg * 8; s < send; ++s) {
        unsigned e2 = *(const unsigned*)(encl + s * 32 + cp * 2);
        float pp = aux[s];
        a0 = fmaf(pp, bfu((unsigned short)(e2 & 0xffffu)), a0);
        a1 = fmaf(pp, bfu((unsigned short)(e2 >> 16)), a1);
      }
      aux[SS + sg * 32 + cp * 2]     = a0;
      aux[SS + sg * 32 + cp * 2 + 1] = a1;
      __syncthreads();
      if (t < 32) {
        float v = 0;
#pragma unroll
        for (int g2 = 0; g2 < 16; ++g2) v += aux[SS + g2 * 32 + t];
        stu16(ctxb + b * HH + sl * 32 + t, f2bf(v * inv));
      }
    }
    GBAR();

    // ---- P4: layer-0 gates + GRU -> h0new (y = pre-staged h0old) ----
    gru_phase(sl, t, sxu, sh0u, ctxb + b * HH, wi0, wh0,
              gi0xb + ((size_t)td * BB + b) * H3, nullptr, bhh0,
              h0new + b * HH);
    GBAR();

    // ---- P5: layer-1 gates + GRU -> outsb[td] (y = reused h1old LDS) ----
    gru_phase(sl, t, sxu, sh1u, h0new + b * HH, wi1, wh1,
              nullptr, bih1, bhh1, outsb + (size_t)td * BB * HH + b * HH);
    GBAR();
  }
#undef GBAR
}

// ---------------------------------------------------------------------------
extern "C" void kernel_launch(void* const* d_in, const int* in_sizes, int n_in,
                              void* d_out, int out_size, void* d_ws,
                              size_t ws_size, hipStream_t stream) {
  const int*   X    = (const int*)  d_in[0];
  const float* enc  = (const float*)d_in[1];
  const float* hid  = (const float*)d_in[2];
  const int*   vlen = (const int*)  d_in[3];
  const float* emb  = (const float*)d_in[4];
  const float* Wq   = (const float*)d_in[5];
  const float* Wk   = (const float*)d_in[6];
  const float* wv   = (const float*)d_in[7];
  const float* Wih0 = (const float*)d_in[8];
  const float* Whh0 = (const float*)d_in[9];
  const float* bih0 = (const float*)d_in[10];
  const float* bhh0 = (const float*)d_in[11];
  const float* Wih1 = (const float*)d_in[12];
  const float* Whh1 = (const float*)d_in[13];
  const float* bih1 = (const float*)d_in[14];
  const float* bhh1 = (const float*)d_in[15];
  const float* Wout = (const float*)d_in[16];
  const float* bout = (const float*)d_in[17];
  float* out = (float*)d_out;

  // ---- workspace (float offsets), ~70.6 MB ----
  float* ws = (float*)d_ws;
  unsigned short* wi0b   = (unsigned short*)ws;                 // 4 gate mats
  unsigned short* wh0b   = wi0b + (size_t)3145728;
  unsigned short* wi1b   = wh0b + (size_t)3145728;
  unsigned short* wh1b   = wi1b + (size_t)3145728;
  unsigned short* wqb    = (unsigned short*)(ws + 6291456);
  unsigned short* gi0xb  = (unsigned short*)(ws + 6815744);
  unsigned short* keysb  = (unsigned short*)(ws + 9961472);
  unsigned short* encb   = (unsigned short*)(ws + 12058624);
  unsigned short* xsb    = (unsigned short*)(ws + 14155776);    // prologue only
  unsigned short* wkb    = (unsigned short*)(ws + 14680064);    // prologue only
  unsigned short* wih0xb = (unsigned short*)(ws + 15204352);    // prologue only
  unsigned short* woutb  = (unsigned short*)ws;                 // overlay
  unsigned short* outsb  = (unsigned short*)(ws + 16384000);
  unsigned short* h0A    = (unsigned short*)(ws + 17432576);
  unsigned short* h0B    = (unsigned short*)(ws + 17448960);
  unsigned short* h1i    = (unsigned short*)(ws + 17465344);
  unsigned short* ctxb   = (unsigned short*)(ws + 17481728);
  float*          partial= ws + 17498112;                       // 131,072 f
  float*          scores = ws + 17629184;                       //   4,096 f
  unsigned*       bar    = (unsigned*)(ws + 17633280);          // 16,896 u32

  k_init<<<322, 256, 0, stream>>>(hid, h0A, h1i, bar);
  k_gather<<<1024, 256, 0, stream>>>(X, emb, xsb);
  // bf16 converts for prologue GEMMs
  k_conv<<<4096, 256, 0, stream>>>(enc, encb, 256, HH);
  k_conv<<<1024, 256, 0, stream>>>(Wk, wkb, 256, HH);
  k_conv<<<3072, 256, 0, stream>>>(Wih0 + HH, wih0xb, 128, HH + EE);
  // keysb = bf16(enc @ Wk^T)
  k_gemm_mfma<<<dim3(8, 32), 256, 0, stream>>>(encb, wkb, nullptr,
                                               (float*)keysb, BB * SS, HH, HH,
                                               0, 1);
  // gi0xb = bf16(xs @ W_ih0[:,H:]^T + b_ih0)
  k_gemm_mfma<<<dim3(24, 16), 256, 0, stream>>>(xsb, wih0xb, bih0,
                                                (float*)gi0xb, TT * BB, H3, EE,
                                                0, 1);
  // recurrent weights -> bf16
  k_conv<<<1024, 256, 0, stream>>>(Wq, wqb, 256, HH);
  k_conv<<<3072, 256, 0, stream>>>(Wih0, wi0b, 256, HH + EE);  // ctx cols only
  k_conv<<<3072, 256, 0, stream>>>(Whh0, wh0b, 256, HH);
  k_conv<<<3072, 256, 0, stream>>>(Wih1, wi1b, 256, HH);
  k_conv<<<3072, 256, 0, stream>>>(Whh1, wh1b, 256, HH);

  // the whole 64-step recurrence, one launch, per-b 32-block group barriers
  k_persist<<<NB, 256, 0, stream>>>(keysb, encb, gi0xb, wqb,
                                    wi0b, wh0b, wi1b, wh1b,
                                    wv, vlen, h1i,
                                    bhh0, bih1, bhh1,
                                    partial, scores, ctxb, h0A, h0B, outsb, bar);

  // Wout -> bf16 into the now-dead overlay, then MFMA logits GEMM
  k_conv<<<32000, 256, 0, stream>>>(Wout, woutb, 256, HH);
  k_gemm_mfma<<<dim3(250, 16), 256, 0, stream>>>(outsb, woutb, bout, out,
                                                 TT * BB, VV, HH, 1, 0);
}